// Round 3
// baseline (1358.352 us; speedup 1.0000x reference)
//
#include <hip/hip_runtime.h>

#define DIM 128
#define GAMMA 12.0f

// One 16-lane group per edge; lane gl owns float4 indices gl and gl+16
// (i.e. dims [gl*4, gl*4+4) and [gl*4+64, gl*4+68)), so each group reads a
// 512 B row as two coalesced 256 B requests, and consecutive groups in a
// wave read CONSECUTIVE edge_emb rows (perfect streaming on the big input).
// The reduction over dst is done with hardware f32 atomics into out.
__global__ __launch_bounds__(256) void edge_kernel(
    const float* __restrict__ node_emb,
    const float* __restrict__ edge_emb,
    const int* __restrict__ src,
    const int* __restrict__ dst,
    float* __restrict__ out,
    int E)
{
    int e = blockIdx.x * 16 + ((int)threadIdx.x >> 4);
    if (e >= E) return;
    int gl = (int)threadIdx.x & 15;

    int s = src[e];
    int d = dst[e];

    const float4* rp = (const float4*)(edge_emb + (size_t)e * DIM);
    const float4* hp = (const float4*)(node_emb + (size_t)s * DIM);
    const float4* tp = (const float4*)(node_emb + (size_t)d * DIM);

    float4 r0 = rp[gl], r1 = rp[gl + 16];
    float4 h0 = hp[gl], h1 = hp[gl + 16];
    float4 t0 = tp[gl], t1 = tp[gl + 16];

    float4 x0, x1;
    x0.x = h0.x + r0.x; x0.y = h0.y + r0.y; x0.z = h0.z + r0.z; x0.w = h0.w + r0.w;
    x1.x = h1.x + r1.x; x1.y = h1.y + r1.y; x1.z = h1.z + r1.z; x1.w = h1.w + r1.w;

    float dd, sq;
    dd = x0.x - t0.x; sq  = dd * dd;
    dd = x0.y - t0.y; sq += dd * dd;
    dd = x0.z - t0.z; sq += dd * dd;
    dd = x0.w - t0.w; sq += dd * dd;
    dd = x1.x - t1.x; sq += dd * dd;
    dd = x1.y - t1.y; sq += dd * dd;
    dd = x1.z - t1.z; sq += dd * dd;
    dd = x1.w - t1.w; sq += dd * dd;

    // reduce across the 16 lanes of this group (xor offsets < 16 stay in-group)
    #pragma unroll
    for (int off = 8; off > 0; off >>= 1)
        sq += __shfl_xor(sq, off, 64);

    float score = 1.0f / (1.0f + expf(sqrtf(sq) - GAMMA));

    // accumulate score * trans into out[d] with HW f32 atomics
    float* op = out + (size_t)d * DIM + gl * 4;
    unsafeAtomicAdd(op + 0,  score * x0.x);
    unsafeAtomicAdd(op + 1,  score * x0.y);
    unsafeAtomicAdd(op + 2,  score * x0.z);
    unsafeAtomicAdd(op + 3,  score * x0.w);
    unsafeAtomicAdd(op + 64, score * x1.x);
    unsafeAtomicAdd(op + 65, score * x1.y);
    unsafeAtomicAdd(op + 66, score * x1.z);
    unsafeAtomicAdd(op + 67, score * x1.w);
}

extern "C" void kernel_launch(void* const* d_in, const int* in_sizes, int n_in,
                              void* d_out, int out_size, void* d_ws, size_t ws_size,
                              hipStream_t stream) {
    const float* node_emb = (const float*)d_in[0];
    const float* edge_emb = (const float*)d_in[1];
    const int*   src      = (const int*)d_in[2];
    const int*   dst      = (const int*)d_in[3];
    float*       out      = (float*)d_out;

    int E = in_sizes[2];

    // out_size is in floats (N = out_size / DIM in the bucketed version)
    hipMemsetAsync(out, 0, (size_t)out_size * sizeof(float), stream);

    int blocks = (E + 15) / 16;   // 16 edges (16-lane groups) per 256-thread block
    edge_kernel<<<blocks, 256, 0, stream>>>(node_emb, edge_emb, src, dst, out, E);
}

// Round 4
// 978.883 us; speedup vs baseline: 1.3877x; 1.3877x over previous
//
#include <hip/hip_runtime.h>
#include <hip/hip_cooperative_groups.h>

namespace cg = cooperative_groups;

#define DIM 128
#define GAMMA 12.0f
#define PREP_BLOCKS 1024
#define PREP_THREADS 256
#define CHUNK 128          // cnt elements per scan chunk (nchunks <= 1024)

// --- Fused preprocessing: zero -> hist+rank -> 3-level scan -> scatter ---
// One cooperative launch, 1024 blocks x 256 threads (4 blocks/CU, co-resident).
__global__ __launch_bounds__(PREP_THREADS, 4) void prep_kernel(
    const int* __restrict__ src, const int* __restrict__ dst,
    int2* __restrict__ sorted2, int* __restrict__ cnt,
    int* __restrict__ offs, int* __restrict__ rank,
    int* __restrict__ bsum, int N, int E)
{
    cg::grid_group grid = cg::this_grid();
    const int t   = (int)threadIdx.x;
    const int tid = (int)blockIdx.x * PREP_THREADS + t;
    const int nth = (int)gridDim.x * PREP_THREADS;
    const int nchunks = (N + CHUNK - 1) / CHUNK;

    __shared__ int sh[PREP_THREADS];

    // Phase 0: zero the histogram
    for (int i = tid; i < N; i += nth) cnt[i] = 0;
    grid.sync();

    // Phase 1: in-degree histogram + per-edge rank (arrival order)
    for (int e = tid; e < E; e += nth)
        rank[e] = atomicAdd(&cnt[dst[e]], 1);
    grid.sync();

    // Phase 2a: per-chunk local exclusive scan -> offs (partial); totals -> bsum
    for (int c = (int)blockIdx.x; c < nchunks; c += (int)gridDim.x) {
        int i = c * CHUNK + t;
        int v = 0;
        if (t < CHUNK && i < N) v = cnt[i];
        sh[t] = (t < CHUNK) ? v : 0;
        __syncthreads();
        for (int off = 1; off < CHUNK; off <<= 1) {
            int u = (t >= off && t < CHUNK) ? sh[t - off] : 0;
            __syncthreads();
            if (t < CHUNK) sh[t] += u;
            __syncthreads();
        }
        if (t < CHUNK && i < N) offs[i] = sh[t] - v;   // local exclusive
        if (t == CHUNK - 1) bsum[c] = sh[t];           // chunk total
        __syncthreads();
    }
    grid.sync();

    // Phase 2b: exclusive scan of bsum[nchunks] (block 0 only, 4 elems/thread)
    if (blockIdx.x == 0) {
        int v4[4]; int s = 0;
        #pragma unroll
        for (int j = 0; j < 4; ++j) {
            int idx = t * 4 + j;
            v4[j] = (idx < nchunks) ? bsum[idx] : 0;
            s += v4[j];
        }
        sh[t] = s;
        __syncthreads();
        for (int off = 1; off < PREP_THREADS; off <<= 1) {
            int u = (t >= off) ? sh[t - off] : 0;
            __syncthreads();
            sh[t] += u;
            __syncthreads();
        }
        int run = sh[t] - s;   // exclusive across threads
        #pragma unroll
        for (int j = 0; j < 4; ++j) {
            int idx = t * 4 + j;
            if (idx < nchunks) bsum[idx] = run;
            run += v4[j];
        }
    }
    grid.sync();

    // Phase 2c: finalize offs with chunk bases
    for (int i = tid; i < N; i += nth) offs[i] += bsum[i / CHUNK];
    grid.sync();

    // Phase 3: deterministic scatter, packing (e, src[e])
    for (int e = tid; e < E; e += nth) {
        int d = dst[e];
        sorted2[offs[d] + rank[e]] = make_int2(e, src[e]);
    }
}

// --- Node phase: one wave per dst node, 4 edges in flight (16 lanes/edge).
// Lane gl of a group owns float4 indices gl and gl+16, so every 16-lane
// load/store of a 512 B row is coalesced. Unchanged from the 528 us version. ---
__global__ __launch_bounds__(256) void node_kernel(
    const float* __restrict__ node_emb,
    const float* __restrict__ edge_emb,
    const int2* __restrict__ sorted2,
    const int* __restrict__ offs,
    float* __restrict__ out,
    int N, int E)
{
    int wave = (blockIdx.x * (int)blockDim.x + (int)threadIdx.x) >> 6;
    int lane = (int)threadIdx.x & 63;
    if (wave >= N) return;

    int g  = lane >> 4;          // edge slot 0..3
    int gl = lane & 15;          // lane within group

    int start = offs[wave];
    int end   = (wave + 1 < N) ? offs[wave + 1] : E;

    const float4* tp = (const float4*)(node_emb + (size_t)wave * DIM);
    float4 t0 = tp[gl];
    float4 t1 = tp[gl + 16];

    float4 a0 = make_float4(0.f, 0.f, 0.f, 0.f);
    float4 a1 = make_float4(0.f, 0.f, 0.f, 0.f);

    int k = start + g;
    int2 es = (k < end) ? sorted2[k] : make_int2(0, 0);
    while (k < end) {
        int kn = k + 4;
        int2 esn = (kn < end) ? sorted2[kn] : es;   // prefetch next slot

        const float4* hp = (const float4*)(node_emb + (size_t)es.y * DIM);
        const float4* rp = (const float4*)(edge_emb + (size_t)es.x * DIM);
        float4 h0 = hp[gl],      h1 = hp[gl + 16];
        float4 r0 = rp[gl],      r1 = rp[gl + 16];

        float4 x0, x1;
        x0.x = h0.x + r0.x; x0.y = h0.y + r0.y; x0.z = h0.z + r0.z; x0.w = h0.w + r0.w;
        x1.x = h1.x + r1.x; x1.y = h1.y + r1.y; x1.z = h1.z + r1.z; x1.w = h1.w + r1.w;

        float dd, sq;
        dd = x0.x - t0.x; sq  = dd * dd;
        dd = x0.y - t0.y; sq += dd * dd;
        dd = x0.z - t0.z; sq += dd * dd;
        dd = x0.w - t0.w; sq += dd * dd;
        dd = x1.x - t1.x; sq += dd * dd;
        dd = x1.y - t1.y; sq += dd * dd;
        dd = x1.z - t1.z; sq += dd * dd;
        dd = x1.w - t1.w; sq += dd * dd;

        #pragma unroll
        for (int off = 8; off > 0; off >>= 1)
            sq += __shfl_xor(sq, off, 64);

        float score = 1.0f / (1.0f + expf(sqrtf(sq) - GAMMA));
        a0.x += score * x0.x; a0.y += score * x0.y; a0.z += score * x0.z; a0.w += score * x0.w;
        a1.x += score * x1.x; a1.y += score * x1.y; a1.z += score * x1.z; a1.w += score * x1.w;

        es = esn; k = kn;
    }

    #pragma unroll
    for (int off = 16; off <= 32; off <<= 1) {
        a0.x += __shfl_xor(a0.x, off, 64); a0.y += __shfl_xor(a0.y, off, 64);
        a0.z += __shfl_xor(a0.z, off, 64); a0.w += __shfl_xor(a0.w, off, 64);
        a1.x += __shfl_xor(a1.x, off, 64); a1.y += __shfl_xor(a1.y, off, 64);
        a1.z += __shfl_xor(a1.z, off, 64); a1.w += __shfl_xor(a1.w, off, 64);
    }

    if (g == 0) {
        float4* op = (float4*)(out + (size_t)wave * DIM);
        op[gl]      = a0;
        op[gl + 16] = a1;
    }
}

extern "C" void kernel_launch(void* const* d_in, const int* in_sizes, int n_in,
                              void* d_out, int out_size, void* d_ws, size_t ws_size,
                              hipStream_t stream) {
    const float* node_emb = (const float*)d_in[0];
    const float* edge_emb = (const float*)d_in[1];
    const int*   src      = (const int*)d_in[2];
    const int*   dst      = (const int*)d_in[3];
    float*       out      = (float*)d_out;

    int E = in_sizes[2];
    int N = out_size / DIM;

    // Workspace: sorted2[E] (int2 at 8B-aligned base) | cnt[N] | offs[N] |
    //            rank[E] | bsum[1024]
    int2* sorted2 = (int2*)d_ws;
    int*  cnt     = (int*)(sorted2 + E);
    int*  offs    = cnt + N;
    int*  rank    = offs + N;
    int*  bsum    = rank + E;

    void* args[] = {(void*)&src, (void*)&dst, (void*)&sorted2, (void*)&cnt,
                    (void*)&offs, (void*)&rank, (void*)&bsum,
                    (void*)&N, (void*)&E};
    hipLaunchCooperativeKernel(reinterpret_cast<void*>(prep_kernel),
                               dim3(PREP_BLOCKS), dim3(PREP_THREADS),
                               args, 0, stream);

    dim3 grid(((size_t)N * 64 + 255) / 256);
    node_kernel<<<grid, 256, 0, stream>>>(node_emb, edge_emb, sorted2, offs,
                                          out, N, E);
}